// Round 18
// baseline (51.962 us; speedup 1.0000x reference)
//
#include <hip/hip_runtime.h>
#include <math.h>

#define N 128
#define HID 512
#define NH (N * HID)                 // 65536
#define SNH ((size_t)N * NH)         // 8388608 elements per s
#define NPAIRS (N * (N + 1) / 2)     // 8256

typedef float vf4 __attribute__((ext_vector_type(4)));
union F4 { vf4 v; float f[4]; };
typedef unsigned int u32t;
typedef unsigned short u16t;

// bf16 pack/unpack (RNE)
__device__ __forceinline__ u32t pk2(float a, float b) {
    u32t ua = __float_as_uint(a), ub = __float_as_uint(b);
    ua = (ua + 0x7FFFu + ((ua >> 16) & 1u)) >> 16;
    ub = (ub + 0x7FFFu + ((ub >> 16) & 1u)) >> 16;
    return ua | (ub << 16);
}
__device__ __forceinline__ void stbf4(u16t* p, F4 t) {
    uint2 u; u.x = pk2(t.f[0], t.f[1]); u.y = pk2(t.f[2], t.f[3]);
    *reinterpret_cast<uint2*>(p) = u;
}
__device__ __forceinline__ F4 ldbf4(const u16t* p) {
    const uint2 u = *reinterpret_cast<const uint2*>(p);
    F4 r;
    r.f[0] = __uint_as_float(u.x << 16);
    r.f[1] = __uint_as_float(u.x & 0xFFFF0000u);
    r.f[2] = __uint_as_float(u.y << 16);
    r.f[3] = __uint_as_float(u.y & 0xFFFF0000u);
    return r;
}

// ---------------------------------------------------------------------------
// K1: stride-free dense-cube partial sums (R17, verbatim).
// ---------------------------------------------------------------------------
__global__ __launch_bounds__(512)
void schur_p1(const float* __restrict__ x, u16t* __restrict__ PScol,
              u16t* __restrict__ PSrow, float* __restrict__ Dg) {
    const int u  = blockIdx.x;            // 0..255
    const int hq = u & 3;
    const int bq = (u >> 2) & 3;
    const int g  = (u >> 4) & 7;
    const int s  = u >> 7;                // 0..1
    const int tid = threadIdx.x;
    const int f   = tid & 31;             // float4 within h-quarter
    const int bg  = tid >> 5;             // 0..15, 2 b's each
    const int b0  = bq * 32 + bg * 2;
    const int hoff = hq * 128 + f * 4;

    const float* xs   = x + (size_t)s * SNH;
    const float* base = xs + (size_t)(g * 16) * NH + b0 * HID + hoff;

    __shared__ F4 rowred[8][16][32];      // 64 KiB

    F4 acc0, acc1;
    acc0.v = (vf4)(0.f); acc1.v = (vf4)(0.f);

    #pragma unroll
    for (int c = 0; c < 2; ++c) {
        #pragma unroll
        for (int al = 0; al < 8; ++al) {
            const float* p = base + (size_t)(c * 8 + al) * NH;
            F4 v0; v0.v = *reinterpret_cast<const vf4*>(p);
            F4 v1; v1.v = *reinterpret_cast<const vf4*>(p + HID);
            acc0.v += v0.v;
            acc1.v += v1.v;
            F4 rs; rs.v = v0.v + v1.v;
            rowred[al][bg][f] = rs;
        }
        __syncthreads();
        if (tid < 256) {
            const int ar = tid >> 5;      // 0..7
            const int f2 = tid & 31;
            F4 t; t.v = (vf4)(0.f);
            #pragma unroll
            for (int k = 0; k < 16; ++k) t.v += rowred[ar][k][f2].v;
            const int a = g * 16 + c * 8 + ar;
            stbf4(PSrow + ((((size_t)s * 4 + bq) * N + a) * HID + hq * 128 + f2 * 4), t);
        }
        __syncthreads();
    }

    stbf4(PScol + ((((size_t)s * 8 + g) * N + b0) * HID + hoff), acc0);
    stbf4(PScol + ((((size_t)s * 8 + g) * N + b0 + 1) * HID + hoff), acc1);

    if (bq == (g >> 1)) {
        const int ar = tid >> 5;          // 0..15
        const int f2 = tid & 31;
        const int a  = g * 16 + ar;
        const vf4 dv = *reinterpret_cast<const vf4*>(
            xs + (size_t)a * NH + a * HID + hq * 128 + f2 * 4);
        *reinterpret_cast<vf4*>(Dg +
            (((size_t)s * N + a) * HID + hq * 128 + f2 * 4)) = dv;
    }
}

// ---------------------------------------------------------------------------
// K2: fold bf16 partials -> stats -> bf16 Xr/Yc + f32 Sv/Db (R17, verbatim).
// ---------------------------------------------------------------------------
__global__ __launch_bounds__(256)
void schur_p2(const u16t* __restrict__ PScol, const u16t* __restrict__ PSrow,
              const float* __restrict__ Dg,
              u16t* __restrict__ Xr, u16t* __restrict__ Yc,
              float* __restrict__ Sv, float* __restrict__ Db) {
    const int bi = blockIdx.x;            // 0..31
    const int s  = bi >> 4;
    const int hc = bi & 15;               // 8 float4 per chunk
    const int tid = threadIdx.x;          // 0..255
    const int iq = tid >> 3;              // 0..31
    const int hf = tid & 7;
    const int h  = (hc * 8 + hf) * 4;     // float offset in [0,512)

    F4 sa[4], sb[4], dg[4];
    F4 T, D; T.v = (vf4)(0.f); D.v = (vf4)(0.f);
    #pragma unroll
    for (int k = 0; k < 4; ++k) {
        const int i = iq + 32 * k;
        F4 acc; acc.v = (vf4)(0.f);
        #pragma unroll
        for (int gg = 0; gg < 8; ++gg)
            acc.v += ldbf4(PScol + (((size_t)s * 8 + gg) * N + i) * HID + h).v;
        sa[k] = acc; T.v += acc.v;
        F4 accb; accb.v = (vf4)(0.f);
        #pragma unroll
        for (int qq = 0; qq < 4; ++qq)
            accb.v += ldbf4(PSrow + (((size_t)s * 4 + qq) * N + i) * HID + h).v;
        sb[k] = accb;
        dg[k].v = *reinterpret_cast<const vf4*>(Dg + ((size_t)s * N + i) * HID + h);
        D.v += dg[k].v;
    }

    __shared__ F4 redT[32][8];
    __shared__ F4 redD[32][8];
    __shared__ F4 shS[8];
    redT[iq][hf] = T;
    redD[iq][hf] = D;
    __syncthreads();
    if (iq == 0) {
        F4 Tt, Dd; Tt.v = (vf4)(0.f); Dd.v = (vf4)(0.f);
        #pragma unroll
        for (int q = 0; q < 32; ++q) { Tt.v += redT[q][hf].v; Dd.v += redD[q][hf].v; }
        F4 sh, db_;
        sh.v  = (Tt.v - Dd.v) * (1.0f / 16256.0f);   // /(n(n-1))
        db_.v = Dd.v * (1.0f / 128.0f);
        *reinterpret_cast<vf4*>(Sv + s * HID + h) = sh.v;
        *reinterpret_cast<vf4*>(Db + s * HID + h) = db_.v;
        shS[hf] = sh;
    }
    __syncthreads();

    const F4 sh = shS[hf];
    const float inv = 1.0f / 16128.0f;    // 1/(n(n-2))
    const size_t base = (size_t)s * N * HID;
    #pragma unroll
    for (int k = 0; k < 4; ++k) {
        const int i = iq + 32 * k;
        F4 r, c, xr, yc;
        r.v = sa[k].v - dg[k].v - 127.0f * sh.v;
        c.v = sb[k].v - dg[k].v - 127.0f * sh.v;
        xr.v = (127.0f * r.v + c.v) * inv;
        yc.v = (127.0f * c.v + r.v) * inv;
        stbf4(Xr + base + (size_t)i * HID + h, xr);
        stbf4(Yc + base + (size_t)i * HID + h, yc);
    }
}

// ---------------------------------------------------------------------------
// K3: TILE-PAIRED output. Block = (s, triangular 8x8 tile-pair (ar<=br)):
// 2*136 = 272 blocks = 8 XCDs x 34 (bijective swizzle). Block reads the dense
// panels x[A8][B8][:], x[B8][A8][:] and writes both out panels — all reads
// AND writes are dense 16KB-contiguous spans (kills the 256KB write comb of
// the pair-list version; same mechanism as p1's R11 dense-cube fix).
// 512 threads = f(128 h-float4) x q(4, 2 a-rows each).
// ---------------------------------------------------------------------------
__global__ __launch_bounds__(512)
void schur_p3(const float* __restrict__ x, const float* __restrict__ w,
              const float* __restrict__ iso,
              const u16t* __restrict__ Xr, const u16t* __restrict__ Yc,
              const float* __restrict__ Sv, const float* __restrict__ Db,
              float* __restrict__ out) {
    const int tid = threadIdx.x;
    const int f   = tid & 127;
    const int q   = tid >> 7;             // 0..3
    const int hoff = f * 4;

    float c[7];
    #pragma unroll
    for (int j = 0; j < 7; ++j) {
        float acc = 0.f;
        #pragma unroll
        for (int i = 0; i < 7; ++i) acc += w[i * 7 + j] * iso[i * 7 + j];
        c[j] = acc;
    }
    const float c1 = c[0], c2 = c[1], c3 = c[2], c4 = c[3], c5 = c[4];
    const float al = 0.5f * (c[5] + c[6]);
    const float be = 0.5f * (c[5] - c[6]);

    // XCD bijective swizzle: 272 = 8 * 34
    const int bid = blockIdx.x;
    const int swz = (bid & 7) * 34 + (bid >> 3);
    const int s   = (swz >= 136) ? 1 : 0;
    const int tp  = swz - s * 136;

    // decode triangular tile-pair tp -> (ar, br), ar <= br, 16 tiles/side
    #define OFF16(r) ((r) * 16 - (((r) * ((r) - 1)) >> 1))
    int ar = 0;
    while (OFF16(ar + 1) <= tp) ++ar;
    const int br = ar + (tp - OFF16(ar));
    const bool diag = (ar == br);

    const size_t sbase    = (size_t)s * SNH;
    const size_t statbase = (size_t)s * N * HID;

    F4 sh; sh.v = *reinterpret_cast<const vf4*>(Sv + (size_t)s * HID + hoff);
    F4 db; db.v = *reinterpret_cast<const vf4*>(Db + (size_t)s * HID + hoff);

    // preload b-tile stats (unrolled -> static register indexing)
    F4 xrb[8], ycb[8];
    #pragma unroll
    for (int bl = 0; bl < 8; ++bl) {
        const int gb = br * 8 + bl;
        xrb[bl] = ldbf4(Xr + statbase + (size_t)gb * HID + hoff);
        ycb[bl] = ldbf4(Yc + statbase + (size_t)gb * HID + hoff);
    }

    #pragma unroll
    for (int aq = 0; aq < 2; ++aq) {
        const int alc = q * 2 + aq;       // local a row 0..7
        const int ga  = ar * 8 + alc;
        const F4 xra = ldbf4(Xr + statbase + (size_t)ga * HID + hoff);
        const F4 yca = ldbf4(Yc + statbase + (size_t)ga * HID + hoff);
        const float* rowA = x   + sbase + (size_t)ga * NH + hoff;   // + b*HID
        float*       orwA = out + sbase + (size_t)ga * NH + hoff;

        #pragma unroll
        for (int bl = 0; bl < 8; ++bl) {
            const int gb = br * 8 + bl;
            if (diag) {
                if (bl < alc) continue;
                if (bl == alc) {          // diagonal element
                    F4 v; v.v = *reinterpret_cast<const vf4*>(rowA + gb * HID);
                    F4 o;
                    #pragma unroll
                    for (int j = 0; j < 4; ++j)
                        o.f[j] = c1 * db.f[j] + c2 * (v.f[j] - db.f[j]);
                    __builtin_nontemporal_store(o.v,
                        reinterpret_cast<vf4*>(orwA + gb * HID));
                    continue;
                }
            }
            F4 va; va.v = *reinterpret_cast<const vf4*>(rowA + gb * HID);
            F4 vb; vb.v = *reinterpret_cast<const vf4*>(
                x + sbase + (size_t)gb * NH + ga * HID + hoff);

            F4 oab, oba;
            #pragma unroll
            for (int j = 0; j < 4; ++j) {
                const float U = va.f[j] - sh.f[j] - xrb[bl].f[j] - yca.f[j];
                const float V = vb.f[j] - sh.f[j] - xra.f[j] - ycb[bl].f[j];
                oab.f[j] = c3 * sh.f[j] + c4 * xrb[bl].f[j] + c5 * yca.f[j] + al * U + be * V;
                oba.f[j] = c3 * sh.f[j] + c4 * xra.f[j] + c5 * ycb[bl].f[j] + al * V + be * U;
            }
            __builtin_nontemporal_store(oab.v,
                reinterpret_cast<vf4*>(orwA + gb * HID));
            __builtin_nontemporal_store(oba.v,
                reinterpret_cast<vf4*>(out + sbase + (size_t)gb * NH + ga * HID + hoff));
        }
    }
}

extern "C" void kernel_launch(void* const* d_in, const int* in_sizes, int n_in,
                              void* d_out, int out_size, void* d_ws, size_t ws_size,
                              hipStream_t stream) {
    const float* x   = (const float*)d_in[0];
    const float* w   = (const float*)d_in[1];
    const float* iso = (const float*)d_in[2];
    float* out = (float*)d_out;
    char* wsb  = (char*)d_ws;

    u16t*  PScol = (u16t*)(wsb);                         // 2 MB
    u16t*  PSrow = (u16t*)(wsb + (4u << 20));            // 1 MB
    float* Dg    = (float*)(wsb + (8u << 20));           // 512 KB
    u16t*  Xr    = (u16t*)(wsb + (12u << 20));           // 256 KB
    u16t*  Yc    = (u16t*)(wsb + (14u << 20));           // 256 KB
    float* Sv    = (float*)(wsb + (16u << 20));          // 4 KB
    float* Db    = (float*)(wsb + (16u << 20) + 65536);  // 4 KB

    schur_p1<<<256, 512, 0, stream>>>(x, PScol, PSrow, Dg);
    schur_p2<<<32, 256, 0, stream>>>(PScol, PSrow, Dg, Xr, Yc, Sv, Db);
    schur_p3<<<272, 512, 0, stream>>>(x, w, iso, Xr, Yc, Sv, Db, out);
}

// Round 19
// 45.032 us; speedup vs baseline: 1.1539x; 1.1539x over previous
//
#include <hip/hip_runtime.h>
#include <math.h>

#define N 128
#define HID 512
#define NH (N * HID)                 // 65536
#define SNH ((size_t)N * NH)         // 8388608 elements per s
#define NPAIRS (N * (N + 1) / 2)     // 8256

typedef float vf4 __attribute__((ext_vector_type(4)));
union F4 { vf4 v; float f[4]; };
typedef unsigned int u32t;
typedef unsigned short u16t;

// bf16 pack/unpack (RNE)
__device__ __forceinline__ u32t pk2(float a, float b) {
    u32t ua = __float_as_uint(a), ub = __float_as_uint(b);
    ua = (ua + 0x7FFFu + ((ua >> 16) & 1u)) >> 16;
    ub = (ub + 0x7FFFu + ((ub >> 16) & 1u)) >> 16;
    return ua | (ub << 16);
}
__device__ __forceinline__ void stbf4(u16t* p, F4 t) {
    uint2 u; u.x = pk2(t.f[0], t.f[1]); u.y = pk2(t.f[2], t.f[3]);
    *reinterpret_cast<uint2*>(p) = u;
}
__device__ __forceinline__ F4 ldbf4(const u16t* p) {
    const uint2 u = *reinterpret_cast<const uint2*>(p);
    F4 r;
    r.f[0] = __uint_as_float(u.x << 16);
    r.f[1] = __uint_as_float(u.x & 0xFFFF0000u);
    r.f[2] = __uint_as_float(u.y << 16);
    r.f[3] = __uint_as_float(u.y & 0xFFFF0000u);
    return r;
}

// ---------------------------------------------------------------------------
// K1: stride-free dense-cube partial sums.
// Block = (s, g=a-16-group, bq=b-quarter, hq=h-quarter): 2*8*4*4 = 256.
// Each block reads its 256KB sub-volume of x exactly once (no power-of-2
// macro-stride combs — the R11 fix that was the session's main win).
// ---------------------------------------------------------------------------
__global__ __launch_bounds__(512)
void schur_p1(const float* __restrict__ x, u16t* __restrict__ PScol,
              u16t* __restrict__ PSrow, float* __restrict__ Dg) {
    const int u  = blockIdx.x;            // 0..255
    const int hq = u & 3;
    const int bq = (u >> 2) & 3;
    const int g  = (u >> 4) & 7;
    const int s  = u >> 7;                // 0..1
    const int tid = threadIdx.x;
    const int f   = tid & 31;             // float4 within h-quarter
    const int bg  = tid >> 5;             // 0..15, 2 b's each
    const int b0  = bq * 32 + bg * 2;
    const int hoff = hq * 128 + f * 4;

    const float* xs   = x + (size_t)s * SNH;
    const float* base = xs + (size_t)(g * 16) * NH + b0 * HID + hoff;

    __shared__ F4 rowred[8][16][32];      // 64 KiB

    F4 acc0, acc1;
    acc0.v = (vf4)(0.f); acc1.v = (vf4)(0.f);

    #pragma unroll
    for (int c = 0; c < 2; ++c) {
        #pragma unroll
        for (int al = 0; al < 8; ++al) {
            const float* p = base + (size_t)(c * 8 + al) * NH;
            F4 v0; v0.v = *reinterpret_cast<const vf4*>(p);
            F4 v1; v1.v = *reinterpret_cast<const vf4*>(p + HID);
            acc0.v += v0.v;
            acc1.v += v1.v;
            F4 rs; rs.v = v0.v + v1.v;
            rowred[al][bg][f] = rs;
        }
        __syncthreads();
        if (tid < 256) {
            const int ar = tid >> 5;      // 0..7
            const int f2 = tid & 31;
            F4 t; t.v = (vf4)(0.f);
            #pragma unroll
            for (int k = 0; k < 16; ++k) t.v += rowred[ar][k][f2].v;
            const int a = g * 16 + c * 8 + ar;
            stbf4(PSrow + ((((size_t)s * 4 + bq) * N + a) * HID + hq * 128 + f2 * 4), t);
        }
        __syncthreads();
    }

    stbf4(PScol + ((((size_t)s * 8 + g) * N + b0) * HID + hoff), acc0);
    stbf4(PScol + ((((size_t)s * 8 + g) * N + b0 + 1) * HID + hoff), acc1);

    if (bq == (g >> 1)) {
        const int ar = tid >> 5;          // 0..15
        const int f2 = tid & 31;
        const int a  = g * 16 + ar;
        const vf4 dv = *reinterpret_cast<const vf4*>(
            xs + (size_t)a * NH + a * HID + hq * 128 + f2 * 4);
        *reinterpret_cast<vf4*>(Dg +
            (((size_t)s * N + a) * HID + hq * 128 + f2 * 4)) = dv;
    }
}

// ---------------------------------------------------------------------------
// K2: fold bf16 partials -> stats -> bf16 Xr/Yc + f32 Sv/Db.
// 32 blocks x 256 threads, all vf4.
// ---------------------------------------------------------------------------
__global__ __launch_bounds__(256)
void schur_p2(const u16t* __restrict__ PScol, const u16t* __restrict__ PSrow,
              const float* __restrict__ Dg,
              u16t* __restrict__ Xr, u16t* __restrict__ Yc,
              float* __restrict__ Sv, float* __restrict__ Db) {
    const int bi = blockIdx.x;            // 0..31
    const int s  = bi >> 4;
    const int hc = bi & 15;               // 8 float4 per chunk
    const int tid = threadIdx.x;          // 0..255
    const int iq = tid >> 3;              // 0..31
    const int hf = tid & 7;
    const int h  = (hc * 8 + hf) * 4;     // float offset in [0,512)

    F4 sa[4], sb[4], dg[4];
    F4 T, D; T.v = (vf4)(0.f); D.v = (vf4)(0.f);
    #pragma unroll
    for (int k = 0; k < 4; ++k) {
        const int i = iq + 32 * k;
        F4 acc; acc.v = (vf4)(0.f);
        #pragma unroll
        for (int gg = 0; gg < 8; ++gg)
            acc.v += ldbf4(PScol + (((size_t)s * 8 + gg) * N + i) * HID + h).v;
        sa[k] = acc; T.v += acc.v;
        F4 accb; accb.v = (vf4)(0.f);
        #pragma unroll
        for (int qq = 0; qq < 4; ++qq)
            accb.v += ldbf4(PSrow + (((size_t)s * 4 + qq) * N + i) * HID + h).v;
        sb[k] = accb;
        dg[k].v = *reinterpret_cast<const vf4*>(Dg + ((size_t)s * N + i) * HID + h);
        D.v += dg[k].v;
    }

    __shared__ F4 redT[32][8];
    __shared__ F4 redD[32][8];
    __shared__ F4 shS[8];
    redT[iq][hf] = T;
    redD[iq][hf] = D;
    __syncthreads();
    if (iq == 0) {
        F4 Tt, Dd; Tt.v = (vf4)(0.f); Dd.v = (vf4)(0.f);
        #pragma unroll
        for (int q = 0; q < 32; ++q) { Tt.v += redT[q][hf].v; Dd.v += redD[q][hf].v; }
        F4 sh, db_;
        sh.v  = (Tt.v - Dd.v) * (1.0f / 16256.0f);   // /(n(n-1))
        db_.v = Dd.v * (1.0f / 128.0f);
        *reinterpret_cast<vf4*>(Sv + s * HID + h) = sh.v;
        *reinterpret_cast<vf4*>(Db + s * HID + h) = db_.v;
        shS[hf] = sh;
    }
    __syncthreads();

    const F4 sh = shS[hf];
    const float inv = 1.0f / 16128.0f;    // 1/(n(n-2))
    const size_t base = (size_t)s * N * HID;
    #pragma unroll
    for (int k = 0; k < 4; ++k) {
        const int i = iq + 32 * k;
        F4 r, c, xr, yc;
        r.v = sa[k].v - dg[k].v - 127.0f * sh.v;
        c.v = sb[k].v - dg[k].v - 127.0f * sh.v;
        xr.v = (127.0f * r.v + c.v) * inv;
        yc.v = (127.0f * c.v + r.v) * inv;
        stbf4(Xr + base + (size_t)i * HID + h, xr);
        stbf4(Yc + base + (size_t)i * HID + h, yc);
    }
}

// ---------------------------------------------------------------------------
// K3: output over triangular pairs; bf16 Xr/Yc loads; XCD bijective swizzle;
// NT stores. 2064 blocks x 256 threads, 8 consecutive pairs per block.
// ---------------------------------------------------------------------------
__global__ __launch_bounds__(256)
void schur_p3(const float* __restrict__ x, const float* __restrict__ w,
              const float* __restrict__ iso,
              const u16t* __restrict__ Xr, const u16t* __restrict__ Yc,
              const float* __restrict__ Sv, const float* __restrict__ Db,
              float* __restrict__ out) {
    const int t  = threadIdx.x;
    const int k  = t >> 7;                // pair slot 0/1
    const int ht = t & 127;
    const int hoff = ht * 4;

    float c[7];
    #pragma unroll
    for (int j = 0; j < 7; ++j) {
        float acc = 0.f;
        #pragma unroll
        for (int i = 0; i < 7; ++i) acc += w[i * 7 + j] * iso[i * 7 + j];
        c[j] = acc;
    }
    const float c1 = c[0], c2 = c[1], c3 = c[2], c4 = c[3], c5 = c[4];
    const float al = 0.5f * (c[5] + c[6]);
    const float be = 0.5f * (c[5] - c[6]);

    const int bid = blockIdx.x;
    const int swz = (bid & 7) * 258 + (bid >> 3);   // 2064 = 8*258, bijective
    const int pg0 = swz * 8;

    #define TRI_OFF(aa) ((aa) * N - (((aa) * ((aa) - 1)) >> 1))
    #pragma unroll
    for (int it = 0; it < 4; ++it) {
        const int pg = pg0 + it * 2 + k;      // global pair id, < 16512
        const int s  = (pg >= NPAIRS) ? 1 : 0;
        const int p  = pg - s * NPAIRS;

        int a = (int)((257.0f - sqrtf((float)(66049 - 8 * p))) * 0.5f);
        if (a < 0) a = 0;
        if (a > N - 1) a = N - 1;
        while (a > 0 && TRI_OFF(a) > p) --a;
        while (TRI_OFF(a + 1) <= p) ++a;
        const int b = a + (p - TRI_OFF(a));

        const size_t sbase    = (size_t)s * SNH;
        const size_t statbase = (size_t)s * N * HID;

        if (a == b) {
            F4 v;  v.v  = *reinterpret_cast<const vf4*>(x + sbase + ((size_t)a * N + a) * HID + hoff);
            F4 db; db.v = *reinterpret_cast<const vf4*>(Db + (size_t)s * HID + hoff);
            F4 o;
            #pragma unroll
            for (int j = 0; j < 4; ++j)
                o.f[j] = c1 * db.f[j] + c2 * (v.f[j] - db.f[j]);
            __builtin_nontemporal_store(o.v,
                reinterpret_cast<vf4*>(out + sbase + ((size_t)a * N + a) * HID + hoff));
            continue;
        }

        F4 va;  va.v  = *reinterpret_cast<const vf4*>(x + sbase + ((size_t)a * N + b) * HID + hoff);
        F4 vb;  vb.v  = *reinterpret_cast<const vf4*>(x + sbase + ((size_t)b * N + a) * HID + hoff);
        F4 xra = ldbf4(Xr + statbase + (size_t)a * HID + hoff);
        F4 xrb = ldbf4(Xr + statbase + (size_t)b * HID + hoff);
        F4 yca = ldbf4(Yc + statbase + (size_t)a * HID + hoff);
        F4 ycb = ldbf4(Yc + statbase + (size_t)b * HID + hoff);
        F4 sh;  sh.v  = *reinterpret_cast<const vf4*>(Sv + (size_t)s * HID + hoff);

        F4 oab, oba;
        #pragma unroll
        for (int j = 0; j < 4; ++j) {
            const float U = va.f[j] - sh.f[j] - xrb.f[j] - yca.f[j];
            const float V = vb.f[j] - sh.f[j] - xra.f[j] - ycb.f[j];
            oab.f[j] = c3 * sh.f[j] + c4 * xrb.f[j] + c5 * yca.f[j] + al * U + be * V;
            oba.f[j] = c3 * sh.f[j] + c4 * xra.f[j] + c5 * ycb.f[j] + al * V + be * U;
        }
        __builtin_nontemporal_store(oab.v,
            reinterpret_cast<vf4*>(out + sbase + ((size_t)a * N + b) * HID + hoff));
        __builtin_nontemporal_store(oba.v,
            reinterpret_cast<vf4*>(out + sbase + ((size_t)b * N + a) * HID + hoff));
    }
}

extern "C" void kernel_launch(void* const* d_in, const int* in_sizes, int n_in,
                              void* d_out, int out_size, void* d_ws, size_t ws_size,
                              hipStream_t stream) {
    const float* x   = (const float*)d_in[0];
    const float* w   = (const float*)d_in[1];
    const float* iso = (const float*)d_in[2];
    float* out = (float*)d_out;
    char* wsb  = (char*)d_ws;

    // byte-offset workspace layout (bf16 partials/stats)
    u16t*  PScol = (u16t*)(wsb);                         // 2 MB
    u16t*  PSrow = (u16t*)(wsb + (4u << 20));            // 1 MB
    float* Dg    = (float*)(wsb + (8u << 20));           // 512 KB
    u16t*  Xr    = (u16t*)(wsb + (12u << 20));           // 256 KB
    u16t*  Yc    = (u16t*)(wsb + (14u << 20));           // 256 KB
    float* Sv    = (float*)(wsb + (16u << 20));          // 4 KB
    float* Db    = (float*)(wsb + (16u << 20) + 65536);  // 4 KB

    schur_p1<<<256, 512, 0, stream>>>(x, PScol, PSrow, Dg);
    schur_p2<<<32, 256, 0, stream>>>(PScol, PSrow, Dg, Xr, Yc, Sv, Db);
    schur_p3<<<2064, 256, 0, stream>>>(x, w, iso, Xr, Yc, Sv, Db, out);
}